// Round 2
// baseline (150.050 us; speedup 1.0000x reference)
//
#include <hip/hip_runtime.h>

#define NB 8
#define NN 2048
#define ND 128

typedef float f32x4 __attribute__((ext_vector_type(4)));
typedef __bf16 bf16x8 __attribute__((ext_vector_type(8)));
typedef unsigned short u16x4 __attribute__((ext_vector_type(4)));

__device__ __forceinline__ unsigned short f2bf(float f) {
  unsigned u = __builtin_bit_cast(unsigned, f);
  u = (u + 0x7FFFu + ((u >> 16) & 1u)) >> 16;
  return (unsigned short)u;
}

// K1: h = x @ W^T + b (fp32). Emit hn = L2norm(h) as bf16 [B*N, D] (row-major)
// and hT = h as bf16 [B, D, N] (feature-major, PV B-operand layout).
__global__ __launch_bounds__(512, 2) void k_linear(
    const float* __restrict__ x, const float* __restrict__ W,
    const float* __restrict__ bias,
    unsigned short* __restrict__ hn, unsigned short* __restrict__ hT) {
  __shared__ __align__(16) float xs[128][68];
  __shared__ __align__(16) float wt[128][128];
  const int tid = threadIdx.x;
  const int rbase = blockIdx.x * 64;
  const int b = rbase >> 11;
  const int nb = rbase & (NN - 1);

#pragma unroll
  for (int j = 0; j < 4; ++j) {
    int f = tid + j * 512;
    int row = f >> 5;
    int kc = (f & 31) << 2;
    f32x4 v = *reinterpret_cast<const f32x4*>(&x[(size_t)(rbase + row) * ND + kc]);
#pragma unroll
    for (int i2 = 0; i2 < 4; ++i2) {
      int k = kc + i2;
      xs[k][row ^ (k & 28)] = v[i2];
    }
  }
#pragma unroll
  for (int j = 0; j < 8; ++j) {
    int f = tid + j * 512;
    int o = f >> 5;
    int i0 = (f & 31) << 2;
    f32x4 v = *reinterpret_cast<const f32x4*>(&W[(size_t)o * ND + i0]);
#pragma unroll
    for (int i2 = 0; i2 < 4; ++i2) {
      int k = i0 + i2;
      wt[k][o ^ (k & 28)] = v[i2];
    }
  }
  __syncthreads();

  const int tc = tid & 31;
  const int tr = tid >> 5;

  float acc[4][4];
#pragma unroll
  for (int r = 0; r < 4; ++r)
#pragma unroll
    for (int c = 0; c < 4; ++c) acc[r][c] = 0.f;

#pragma unroll 4
  for (int k = 0; k < 128; ++k) {
    const int sw = k & 28;
    f32x4 xv = *reinterpret_cast<const f32x4*>(&xs[k][(tr * 4) ^ sw]);
    f32x4 wv = *reinterpret_cast<const f32x4*>(&wt[k][(tc * 4) ^ sw]);
#pragma unroll
    for (int r = 0; r < 4; ++r)
#pragma unroll
      for (int c = 0; c < 4; ++c) acc[r][c] += xv[r] * wv[c];
  }

  f32x4 bv = *reinterpret_cast<const f32x4*>(&bias[tc * 4]);
#pragma unroll
  for (int r = 0; r < 4; ++r)
#pragma unroll
    for (int c = 0; c < 4; ++c) acc[r][c] += bv[c];

  float inv[4];
#pragma unroll
  for (int r = 0; r < 4; ++r) {
    float s = acc[r][0] * acc[r][0] + acc[r][1] * acc[r][1] +
              acc[r][2] * acc[r][2] + acc[r][3] * acc[r][3];
#pragma unroll
    for (int d = 1; d < 32; d <<= 1) s += __shfl_xor(s, d, 32);
    inv[r] = 1.f / fmaxf(sqrtf(s), 1e-12f);
  }

#pragma unroll
  for (int r = 0; r < 4; ++r) {
    u16x4 hv;
#pragma unroll
    for (int c = 0; c < 4; ++c) hv[c] = f2bf(acc[r][c] * inv[r]);
    *reinterpret_cast<u16x4*>(&hn[(size_t)(rbase + tr * 4 + r) * ND + tc * 4]) = hv;
  }
#pragma unroll
  for (int c = 0; c < 4; ++c) {
    u16x4 tv;
#pragma unroll
    for (int r = 0; r < 4; ++r) tv[r] = f2bf(acc[r][c]);
    *reinterpret_cast<u16x4*>(
        &hT[((size_t)b * ND + tc * 4 + c) * NN + nb + tr * 4]) = tv;
  }
}

// K2: fused out = relu((edge * (hn hn^T)) @ h).
// 512 blocks (b, qtile32) x 8 waves; wq = w&1 picks 16 q-rows, wk = w>>1
// picks a 512-key quarter -> 16 waves/CU. S^T = K Q^T so the gate's edge
// reads are 4 consecutive floats per lane (f32x4), prefetched a tile ahead.
__global__ __launch_bounds__(512, 4) void k_fused(
    const float* __restrict__ edge,
    const unsigned short* __restrict__ hn,
    const unsigned short* __restrict__ hT,
    float* __restrict__ out) {
  __shared__ __align__(16) unsigned short p_lds[8][16][68];  // per-wave P tile
  __shared__ __align__(16) float red[2][2][16][132];         // wk-reduce ping-pong
  const int tid = threadIdx.x;
  const int w = tid >> 6;
  const int l = tid & 63;
  const int m = l & 15;
  const int g = l >> 4;
  const int wq = w & 1;   // q sub-tile (16 rows)
  const int wk = w >> 1;  // key quarter (512 keys)

  const int bid = blockIdx.x;
  const int qt = bid & 63;
  const int b = bid >> 6;
  const int q0 = qt * 32 + wq * 16;

  const unsigned short* hnb = hn + (size_t)b * NN * ND;

  // Q as B-fragment: col = m -> q-row q0+m, k = g*8 (+32*kst)
  bf16x8 bq[4];
  {
    const unsigned short* qp = hnb + (size_t)(q0 + m) * ND + g * 8;
#pragma unroll
    for (int kst = 0; kst < 4; ++kst)
      bq[kst] = *reinterpret_cast<const bf16x8*>(qp + kst * 32);
  }

  f32x4 acc_o[8];
#pragma unroll
  for (int i = 0; i < 8; ++i) acc_o[i] = (f32x4){0.f, 0.f, 0.f, 0.f};

  // edge row for this lane's q (= q0+m), within this wave's key quarter
  const float* ep = edge + (size_t)b * NN * NN + (size_t)(q0 + m) * NN + wk * 512;
  const unsigned short* vbase = hT + ((size_t)b * ND + m) * NN;

  f32x4 eg[4];
#pragma unroll
  for (int ct = 0; ct < 4; ++ct)
    eg[ct] = *reinterpret_cast<const f32x4*>(ep + ct * 16 + g * 4);

  for (int kt = 0; kt < 8; ++kt) {
    const int kb = wk * 512 + kt * 64;

    f32x4 egn[4];
    if (kt < 7) {
      const float* epn = ep + (kt + 1) * 64;
#pragma unroll
      for (int ct = 0; ct < 4; ++ct)
        egn[ct] = *reinterpret_cast<const f32x4*>(epn + ct * 16 + g * 4);
    }

    // S^T = K Q^T : rows = keys, cols = q. A = K rows, B = Q.
    f32x4 st[4];
#pragma unroll
    for (int ct = 0; ct < 4; ++ct) {
      st[ct] = (f32x4){0.f, 0.f, 0.f, 0.f};
      const unsigned short* kp = hnb + (size_t)(kb + ct * 16 + m) * ND + g * 8;
#pragma unroll
      for (int kst = 0; kst < 4; ++kst) {
        bf16x8 ak = *reinterpret_cast<const bf16x8*>(kp + kst * 32);
        st[ct] = __builtin_amdgcn_mfma_f32_16x16x32_bf16(ak, bq[kst], st[ct], 0, 0, 0);
      }
    }

    // gate: P^T[key = kb+ct*16+g*4+r][q = q0+m]; edge f32x4 covers r=0..3.
    // pack as P[q][key] in LDS (row = q-sub = m).
#pragma unroll
    for (int ct = 0; ct < 4; ++ct) {
      u16x4 pv;
#pragma unroll
      for (int r = 0; r < 4; ++r) pv[r] = f2bf(eg[ct][r] * st[ct][r]);
      *reinterpret_cast<u16x4*>(&p_lds[w][m][ct * 16 + g * 4]) = pv;
    }
#pragma unroll
    for (int ct = 0; ct < 4; ++ct) eg[ct] = egn[ct];

    // out += P @ h : A = P from LDS (row = q = m), B = hT (col = feature = m)
#pragma unroll
    for (int kst2 = 0; kst2 < 2; ++kst2) {
      bf16x8 ap = *reinterpret_cast<const bf16x8*>(&p_lds[w][m][kst2 * 32 + g * 8]);
      const unsigned short* vp = vbase + kb + kst2 * 32 + g * 8;
#pragma unroll
      for (int ct2 = 0; ct2 < 8; ++ct2) {
        bf16x8 bv2 = *reinterpret_cast<const bf16x8*>(vp + (size_t)ct2 * 16 * NN);
        acc_o[ct2] = __builtin_amdgcn_mfma_f32_16x16x32_bf16(ap, bv2, acc_o[ct2], 0, 0, 0);
      }
    }
  }

  // reduce the 4 key-quarters: wk1->slot0, wk2->slot1; wk0 adds; wk3->slot0; wk0 adds.
  if (wk == 1 || wk == 2) {
    const int slot = wk - 1;
#pragma unroll
    for (int ct2 = 0; ct2 < 8; ++ct2)
#pragma unroll
      for (int r = 0; r < 4; ++r)
        red[wq][slot][g * 4 + r][ct2 * 16 + m] = acc_o[ct2][r];
  }
  __syncthreads();
  if (wk == 0) {
#pragma unroll
    for (int ct2 = 0; ct2 < 8; ++ct2)
#pragma unroll
      for (int r = 0; r < 4; ++r)
        acc_o[ct2][r] += red[wq][0][g * 4 + r][ct2 * 16 + m] +
                         red[wq][1][g * 4 + r][ct2 * 16 + m];
  }
  __syncthreads();
  if (wk == 3) {
#pragma unroll
    for (int ct2 = 0; ct2 < 8; ++ct2)
#pragma unroll
      for (int r = 0; r < 4; ++r)
        red[wq][0][g * 4 + r][ct2 * 16 + m] = acc_o[ct2][r];
  }
  __syncthreads();
  if (wk == 0) {
    float* ob = out + ((size_t)b * NN + q0) * ND;
#pragma unroll
    for (int ct2 = 0; ct2 < 8; ++ct2)
#pragma unroll
      for (int r = 0; r < 4; ++r) {
        float v = acc_o[ct2][r] + red[wq][0][g * 4 + r][ct2 * 16 + m];
        ob[(g * 4 + r) * ND + ct2 * 16 + m] = fmaxf(v, 0.f);
      }
  }
}

extern "C" void kernel_launch(void* const* d_in, const int* in_sizes, int n_in,
                              void* d_out, int out_size, void* d_ws, size_t ws_size,
                              hipStream_t stream) {
  const float* x = (const float*)d_in[0];
  const float* edge = (const float*)d_in[1];
  const float* W = (const float*)d_in[2];
  const float* bias = (const float*)d_in[3];
  float* out = (float*)d_out;

  unsigned short* hn = (unsigned short*)d_ws;
  unsigned short* hT = hn + (size_t)NB * NN * ND;

  k_linear<<<dim3((NB * NN) / 64), dim3(512), 0, stream>>>(x, W, bias, hn, hT);
  k_fused<<<dim3(NB * (NN / 32)), dim3(512), 0, stream>>>(edge, hn, hT, out);
}